// Round 1
// baseline (6688.411 us; speedup 1.0000x reference)
//
#include <hip/hip_runtime.h>
#include <math.h>

#define NN 50000
#define TT 12
#define EE 800000
#define DIM 128

__device__ __forceinline__ float sigmoidf_(float x) { return 1.0f / (1.0f + expf(-x)); }
__device__ __forceinline__ float geluf_(float x) {
  return 0.5f * x * (1.0f + erff(x * 0.70710678118654752440f));
}

// ---------------- graph preprocessing ----------------

__global__ void deg_kernel(const int* __restrict__ src, const int* __restrict__ dst,
                           int* __restrict__ ds, int* __restrict__ dd) {
  int e = blockIdx.x * 256 + threadIdx.x;
  if (e < EE) {
    atomicAdd(&ds[src[e]], 1);
    atomicAdd(&dd[dst[e]], 1);
  }
}

__global__ void norm_kernel(const int* __restrict__ ds, const int* __restrict__ dd,
                            float* __restrict__ ns, float* __restrict__ nd) {
  int i = blockIdx.x * 256 + threadIdx.x;
  if (i < NN) {
    ns[i] = rsqrtf((float)(ds[i] > 1 ? ds[i] : 1));
    nd[i] = rsqrtf((float)(dd[i] > 1 ? dd[i] : 1));
  }
}

// single-block exclusive scan over N counts -> row_ptr[N+1]
__global__ void scan_kernel(const int* __restrict__ cnt, int* __restrict__ row_ptr, int n) {
  __shared__ int sm[1024];
  __shared__ int carry;
  int tid = threadIdx.x;
  if (tid == 0) carry = 0;
  __syncthreads();
  for (int base = 0; base < n; base += 1024) {
    int v = (base + tid < n) ? cnt[base + tid] : 0;
    sm[tid] = v;
    __syncthreads();
    for (int off = 1; off < 1024; off <<= 1) {
      int t = (tid >= off) ? sm[tid - off] : 0;
      __syncthreads();
      sm[tid] += t;
      __syncthreads();
    }
    int incl = sm[tid];
    if (base + tid < n) row_ptr[base + tid] = carry + incl - v;
    int tot = sm[1023];
    __syncthreads();
    if (tid == 0) carry += tot;
    __syncthreads();
  }
  if (tid == 0) row_ptr[n] = carry;
}

__global__ void csr_kernel(const int* __restrict__ src, const int* __restrict__ dst,
                           const int* __restrict__ row_ptr, int* __restrict__ fill,
                           int* __restrict__ col) {
  int e = blockIdx.x * 256 + threadIdx.x;
  if (e < EE) {
    int d = dst[e];
    int pos = row_ptr[d] + atomicAdd(&fill[d], 1);
    col[pos] = src[e];
  }
}

// ---------------- SpMM: out[d] = nd[d] * sum_{s in row d} ns[s] * x[s] ----------------
// one wave (64 lanes) per dst row, float2 per lane = 128 feats

__global__ __launch_bounds__(256) void spmm_kernel(
    const float* __restrict__ x, int ldx,
    const int* __restrict__ row_ptr, const int* __restrict__ col,
    const float* __restrict__ ns, const float* __restrict__ nd,
    float* __restrict__ out) {
  int w = (blockIdx.x * 256 + threadIdx.x) >> 6;
  int lane = threadIdx.x & 63;
  if (w >= NN) return;
  int beg = row_ptr[w], end = row_ptr[w + 1];
  float ax = 0.f, ay = 0.f;
  for (int j = beg; j < end; j++) {
    int s = col[j];
    float sc = ns[s];
    const float2 v = *(const float2*)(x + (size_t)s * ldx + (lane << 1));
    ax += sc * v.x;
    ay += sc * v.y;
  }
  float sc2 = nd[w];
  float2 o;
  o.x = ax * sc2;
  o.y = ay * sc2;
  *(float2*)(out + (size_t)w * DIM + (lane << 1)) = o;
}

// ---------------- fp32 GEMM, 128x128 tile, 8x8 micro, K = 128 (x2 if DUAL) ----------------
// TRANSB: B is (Ncols x 128) row-major (i.e. we compute A @ B^T); else B is (128 x 128) row-major.

#define KC 16
#define LDP 132

template <bool TRANSB, bool GELU, bool DUAL>
__global__ __launch_bounds__(256) void gemm_k128(
    const float* __restrict__ A0, int lda0, const float* __restrict__ B0,
    const float* __restrict__ A1, int lda1, const float* __restrict__ B1,
    const float* __restrict__ bias0, const float* __restrict__ bias1,
    float* __restrict__ C, int ldc, int M) {
  __shared__ float As[KC][LDP];
  __shared__ float Bs[KC][LDP];
  const int tid = threadIdx.x;
  const int tx = tid & 15;
  const int ty = tid >> 4;
  const int row0 = blockIdx.x * 128;
  const int col0 = blockIdx.y * 128;

  float acc[8][8];
  for (int i = 0; i < 8; i++)
    for (int j = 0; j < 8; j++) acc[i][j] = 0.f;

#pragma unroll
  for (int seg = 0; seg < (DUAL ? 2 : 1); seg++) {
    const float* A = seg ? A1 : A0;
    const float* B = seg ? B1 : B0;
    const int lda = seg ? lda1 : lda0;
    for (int k0 = 0; k0 < 128; k0 += KC) {
      // stage A tile (128 rows x KC), transposed into As[k][m]
      {
        int idx = tid;
#pragma unroll
        for (int it = 0; it < 2; it++) {
          int m = idx >> 2;
          int kq = (idx & 3) * 4;
          int gr = row0 + m;
          if (gr >= M) gr = M - 1;
          float4 v = *(const float4*)(A + (size_t)gr * lda + k0 + kq);
          As[kq + 0][m] = v.x;
          As[kq + 1][m] = v.y;
          As[kq + 2][m] = v.z;
          As[kq + 3][m] = v.w;
          idx += 256;
        }
      }
      // stage B tile into Bs[k][n]
      if (!TRANSB) {
        int idx = tid;
#pragma unroll
        for (int it = 0; it < 8; it++) {
          int n = idx & 127;
          int k = idx >> 7;
          Bs[k][n] = B[(size_t)(k0 + k) * 128 + col0 + n];
          idx += 256;
        }
      } else {
        int idx = tid;
#pragma unroll
        for (int it = 0; it < 2; it++) {
          int n = idx >> 2;
          int kq = (idx & 3) * 4;
          float4 v = *(const float4*)(B + (size_t)(col0 + n) * 128 + k0 + kq);
          Bs[kq + 0][n] = v.x;
          Bs[kq + 1][n] = v.y;
          Bs[kq + 2][n] = v.z;
          Bs[kq + 3][n] = v.w;
          idx += 256;
        }
      }
      __syncthreads();
#pragma unroll
      for (int k = 0; k < KC; k++) {
        float4 a0 = *(const float4*)&As[k][ty * 8];
        float4 a1 = *(const float4*)&As[k][ty * 8 + 4];
        float4 b0 = *(const float4*)&Bs[k][tx * 8];
        float4 b1 = *(const float4*)&Bs[k][tx * 8 + 4];
        float a[8] = {a0.x, a0.y, a0.z, a0.w, a1.x, a1.y, a1.z, a1.w};
        float b[8] = {b0.x, b0.y, b0.z, b0.w, b1.x, b1.y, b1.z, b1.w};
#pragma unroll
        for (int i = 0; i < 8; i++)
#pragma unroll
          for (int j = 0; j < 8; j++) acc[i][j] += a[i] * b[j];
      }
      __syncthreads();
    }
  }

#pragma unroll
  for (int i = 0; i < 8; i++) {
    int gr = row0 + ty * 8 + i;
    if (gr < M) {
      float o[8];
#pragma unroll
      for (int j = 0; j < 8; j++) {
        int gc = col0 + tx * 8 + j;
        float v = acc[i][j] + bias0[gc];
        if (DUAL) v += bias1[gc];
        if (GELU) v = geluf_(v);
        o[j] = v;
      }
      float4* cp4 = (float4*)(C + (size_t)gr * ldc + col0 + tx * 8);
      cp4[0] = make_float4(o[0], o[1], o[2], o[3]);
      cp4[1] = make_float4(o[4], o[5], o[6], o[7]);
    }
  }
}

// ---------------- column mean over N rows (hs output) ----------------

__global__ void colmean_kernel(const float* __restrict__ x, float* __restrict__ out) {
  int cc = threadIdx.x & 127;
  int half = threadIdx.x >> 7;
  float s = 0.f;
  for (int r = blockIdx.x * 2 + half; r < NN; r += 512)
    s += x[(size_t)r * DIM + cc];
  __shared__ float sm[256];
  sm[threadIdx.x] = s;
  __syncthreads();
  if (threadIdx.x < 128)
    atomicAdd(&out[cc], (sm[threadIdx.x] + sm[threadIdx.x + 128]) * (1.0f / NN));
}

// ---------------- LSTM pointwise + running time-mean of h ----------------

__global__ void lstm_pw(const float* __restrict__ g4, float* __restrict__ c,
                        float* __restrict__ hbuf, float* __restrict__ acc, int mode) {
  int i = blockIdx.x * 256 + threadIdx.x;
  if (i >= NN * DIM) return;
  int n = i >> 7, cc = i & 127;
  const float* g = g4 + (size_t)n * 512;
  float ig = sigmoidf_(g[cc]);
  float fg = sigmoidf_(g[DIM + cc]);
  float gg = tanhf(g[2 * DIM + cc]);
  float og = sigmoidf_(g[3 * DIM + cc]);
  float cprev = (mode == 0) ? 0.f : c[i];
  float cn = fg * cprev + ig * gg;
  float ho = og * tanhf(cn);
  c[i] = cn;
  hbuf[i] = ho;
  if (mode == 0) acc[i] = ho;
  else if (mode == 1) acc[i] += ho;
  else acc[i] = (acc[i] + ho) * (1.0f / TT);
}

// ---------------- host ----------------

extern "C" void kernel_launch(void* const* d_in, const int* in_sizes, int n_in,
                              void* d_out, int out_size, void* d_ws, size_t ws_size,
                              hipStream_t stream) {
  const float* h   = (const float*)d_in[0];
  const int*   src = (const int*)d_in[1];
  const int*   dst = (const int*)d_in[2];
  const float* Wg1 = (const float*)d_in[3];
  const float* bg1 = (const float*)d_in[4];
  const float* Wg2 = (const float*)d_in[5];
  const float* bg2 = (const float*)d_in[6];
  const float* wih = (const float*)d_in[7];
  const float* whh = (const float*)d_in[8];
  const float* bih = (const float*)d_in[9];
  const float* bhh = (const float*)d_in[10];

  float* out = (float*)d_out;
  float* hs_out = out;            // 12*128
  float* ht_out = out + TT * DIM; // N*128

  char* p = (char*)d_ws;
  auto alloc = [&](size_t bytes) -> void* {
    void* r = (void*)p;
    p += (bytes + 255) & ~(size_t)255;
    return r;
  };
  float* bufM  = (float*)alloc((size_t)NN * DIM * 4);
  float* bufX  = (float*)alloc((size_t)NN * DIM * 4);
  float* hp    = (float*)alloc((size_t)NN * DIM * 4);
  float* cp    = (float*)alloc((size_t)NN * DIM * 4);
  float* gates = (float*)alloc((size_t)NN * 4 * DIM * 4);
  float* ns    = (float*)alloc(NN * 4);
  float* nd    = (float*)alloc(NN * 4);
  int* degs    = (int*)alloc(NN * 4);
  int* degd    = (int*)alloc(NN * 4);
  int* rowp    = (int*)alloc((NN + 1) * 4);
  int* colx    = (int*)alloc(EE * 4);

  hipMemsetAsync(degs, 0, NN * 4, stream);
  hipMemsetAsync(degd, 0, NN * 4, stream);
  hipMemsetAsync(hs_out, 0, TT * DIM * 4, stream);
  hipMemsetAsync(hp, 0, (size_t)NN * DIM * 4, stream);

  deg_kernel<<<(EE + 255) / 256, 256, 0, stream>>>(src, dst, degs, degd);
  norm_kernel<<<(NN + 255) / 256, 256, 0, stream>>>(degs, degd, ns, nd);
  scan_kernel<<<1, 1024, 0, stream>>>(degd, rowp, NN);
  hipMemsetAsync(degs, 0, NN * 4, stream);  // reuse as fill counters
  csr_kernel<<<(EE + 255) / 256, 256, 0, stream>>>(src, dst, rowp, degs, colx);

  dim3 gconv((NN + 127) / 128, 1);
  dim3 ggate((NN + 127) / 128, 4);

  for (int i = 0; i < TT; i++) {
    spmm_kernel<<<(NN + 3) / 4, 256, 0, stream>>>(h + (size_t)i * DIM, TT * DIM, rowp, colx, ns, nd, bufM);
    gemm_k128<false, true, false><<<gconv, 256, 0, stream>>>(
        bufM, DIM, Wg1, nullptr, 0, nullptr, bg1, nullptr, bufX, DIM, NN);
    spmm_kernel<<<(NN + 3) / 4, 256, 0, stream>>>(bufX, DIM, rowp, colx, ns, nd, bufM);
    gemm_k128<false, true, false><<<gconv, 256, 0, stream>>>(
        bufM, DIM, Wg2, nullptr, 0, nullptr, bg2, nullptr, bufX, DIM, NN);
    colmean_kernel<<<256, 256, 0, stream>>>(bufX, hs_out + i * DIM);
  }

  for (int t = 0; t < TT; t++) {
    gemm_k128<true, false, true><<<ggate, 256, 0, stream>>>(
        h + (size_t)t * DIM, TT * DIM, wih, hp, DIM, whh, bih, bhh, gates, 4 * DIM, NN);
    int mode = (t == 0) ? 0 : (t == TT - 1 ? 2 : 1);
    lstm_pw<<<(NN * DIM + 255) / 256, 256, 0, stream>>>(gates, cp, hp, ht_out, mode);
  }
}

// Round 2
// 4033.810 us; speedup vs baseline: 1.6581x; 1.6581x over previous
//
#include <hip/hip_runtime.h>
#include <math.h>

#define NN 50000
#define TT 12
#define EE 800000
#define DIM 128

typedef short bf16x8 __attribute__((ext_vector_type(8)));
typedef float f32x4 __attribute__((ext_vector_type(4)));

__device__ __forceinline__ float sigmoidf_(float x) { return 1.0f / (1.0f + expf(-x)); }
__device__ __forceinline__ float geluf_(float x) {
  return 0.5f * x * (1.0f + erff(x * 0.70710678118654752440f));
}
__device__ __forceinline__ unsigned short f2b(float f) {
  union { float f; unsigned u; } v;
  v.f = f;
  unsigned r = (v.u + 0x7fffu + ((v.u >> 16) & 1u)) >> 16;
  return (unsigned short)r;
}
__device__ __forceinline__ float b2f(unsigned short b) {
  union { unsigned u; float f; } v;
  v.u = ((unsigned)b) << 16;
  return v.f;
}

// ---------------- graph preprocessing ----------------

__global__ void deg_kernel(const int* __restrict__ src, const int* __restrict__ dst,
                           int* __restrict__ ds, int* __restrict__ dd) {
  int e = blockIdx.x * 256 + threadIdx.x;
  if (e < EE) {
    atomicAdd(&ds[src[e]], 1);
    atomicAdd(&dd[dst[e]], 1);
  }
}

__global__ void norm_kernel(const int* __restrict__ ds, const int* __restrict__ dd,
                            float* __restrict__ ns, float* __restrict__ nd) {
  int i = blockIdx.x * 256 + threadIdx.x;
  if (i < NN) {
    ns[i] = rsqrtf((float)(ds[i] > 1 ? ds[i] : 1));
    nd[i] = rsqrtf((float)(dd[i] > 1 ? dd[i] : 1));
  }
}

__global__ void scan_kernel(const int* __restrict__ cnt, int* __restrict__ row_ptr, int n) {
  __shared__ int sm[1024];
  __shared__ int carry;
  int tid = threadIdx.x;
  if (tid == 0) carry = 0;
  __syncthreads();
  for (int base = 0; base < n; base += 1024) {
    int v = (base + tid < n) ? cnt[base + tid] : 0;
    sm[tid] = v;
    __syncthreads();
    for (int off = 1; off < 1024; off <<= 1) {
      int t = (tid >= off) ? sm[tid - off] : 0;
      __syncthreads();
      sm[tid] += t;
      __syncthreads();
    }
    int incl = sm[tid];
    if (base + tid < n) row_ptr[base + tid] = carry + incl - v;
    int tot = sm[1023];
    __syncthreads();
    if (tid == 0) carry += tot;
    __syncthreads();
  }
  if (tid == 0) row_ptr[n] = carry;
}

__global__ void csr_kernel(const int* __restrict__ src, const int* __restrict__ dst,
                           const int* __restrict__ row_ptr, int* __restrict__ fill,
                           int* __restrict__ col) {
  int e = blockIdx.x * 256 + threadIdx.x;
  if (e < EE) {
    int d = dst[e];
    int pos = row_ptr[d] + atomicAdd(&fill[d], 1);
    col[pos] = src[e];
  }
}

// ---------------- weight prep: bf16 transposed weights, fused gate bias ----------------

__global__ void prep_w(const float* __restrict__ Wg1, const float* __restrict__ Wg2,
                       const float* __restrict__ wih, const float* __restrict__ whh,
                       const float* __restrict__ bih, const float* __restrict__ bhh,
                       unsigned short* __restrict__ W1bt, unsigned short* __restrict__ W2bt,
                       unsigned short* __restrict__ Bc, float* __restrict__ bgate) {
  int i = blockIdx.x * 256 + threadIdx.x;
  if (i < 16384) {
    int n = i >> 7, k = i & 127;
    W1bt[n * 128 + k] = f2b(Wg1[k * 128 + n]);
    W2bt[n * 128 + k] = f2b(Wg2[k * 128 + n]);
  }
  int j = i - 16384;
  if (j >= 0 && j < 131072) {
    int n = j >> 8, k = j & 255;
    Bc[j] = f2b(k < 128 ? wih[n * 128 + k] : whh[n * 128 + (k - 128)]);
  }
  if (i < 512) bgate[i] = bih[i] + bhh[i];
}

// ---------------- MFMA GEMM core pieces ----------------
// 128x128 tile, 4 waves (2x2), each wave 64x64 via 4x4 tiles of 16x16x32 bf16.
// LDS row stride 40 bf16 (pad) -> 2-way max bank aliasing (free).

#define LDT 40

// K1: z1t[bf16, N x 128] = (ns[.] * h_t[f32, lda 1536]) @ W1bt^T
__global__ __launch_bounds__(256) void gemm_scaleA_f32(
    const float* __restrict__ A, const float* __restrict__ ns,
    const unsigned short* __restrict__ Bt, unsigned short* __restrict__ C, int M) {
  __shared__ unsigned short As[128 * LDT];
  __shared__ unsigned short Bs[128 * LDT];
  const int tid = threadIdx.x;
  const int lane = tid & 63, wid = tid >> 6;
  const int quad = lane >> 4, l16 = lane & 15;
  const int row0 = blockIdx.x * 128;
  const int wm = (wid >> 1) * 64, wn = (wid & 1) * 64;
  f32x4 acc[4][4] = {};
  for (int k0 = 0; k0 < 128; k0 += 32) {
#pragma unroll
    for (int rds = 0; rds < 2; rds++) {
      int idx = (rds * 256 + tid) * 8;
      int m = idx >> 5, c = idx & 31;
      int gr = row0 + m;
      if (gr >= M) gr = M - 1;
      float s = ns[gr];
      const float4 va = *(const float4*)(A + (size_t)gr * (TT * DIM) + k0 + c);
      const float4 vb = *(const float4*)(A + (size_t)gr * (TT * DIM) + k0 + c + 4);
      unsigned short* d = &As[m * LDT + c];
      d[0] = f2b(va.x * s); d[1] = f2b(va.y * s); d[2] = f2b(va.z * s); d[3] = f2b(va.w * s);
      d[4] = f2b(vb.x * s); d[5] = f2b(vb.y * s); d[6] = f2b(vb.z * s); d[7] = f2b(vb.w * s);
      // B tile
      int n = m;
      *(uint4*)(&Bs[n * LDT + c]) = *(const uint4*)(Bt + n * 128 + k0 + c);
    }
    __syncthreads();
    bf16x8 af[4], bfr[4];
#pragma unroll
    for (int im = 0; im < 4; im++)
      af[im] = *(const bf16x8*)(&As[(wm + im * 16 + l16) * LDT + quad * 8]);
#pragma unroll
    for (int in = 0; in < 4; in++)
      bfr[in] = *(const bf16x8*)(&Bs[(wn + in * 16 + l16) * LDT + quad * 8]);
#pragma unroll
    for (int im = 0; im < 4; im++)
#pragma unroll
      for (int in = 0; in < 4; in++)
        acc[im][in] = __builtin_amdgcn_mfma_f32_16x16x32_bf16(af[im], bfr[in], acc[im][in], 0, 0, 0);
    __syncthreads();
  }
#pragma unroll
  for (int im = 0; im < 4; im++)
#pragma unroll
    for (int r = 0; r < 4; r++) {
      int row = row0 + wm + im * 16 + quad * 4 + r;
      if (row < M)
#pragma unroll
        for (int in = 0; in < 4; in++)
          C[(size_t)row * 128 + wn + in * 16 + l16] = f2b(acc[im][in][r]);
    }
}

// K2: z2[bf16] = y1s[bf16, lda 128] @ W2bt^T
__global__ __launch_bounds__(256) void gemm_bf16A(
    const unsigned short* __restrict__ A, const unsigned short* __restrict__ Bt,
    unsigned short* __restrict__ C, int M) {
  __shared__ unsigned short As[128 * LDT];
  __shared__ unsigned short Bs[128 * LDT];
  const int tid = threadIdx.x;
  const int lane = tid & 63, wid = tid >> 6;
  const int quad = lane >> 4, l16 = lane & 15;
  const int row0 = blockIdx.x * 128;
  const int wm = (wid >> 1) * 64, wn = (wid & 1) * 64;
  f32x4 acc[4][4] = {};
  for (int k0 = 0; k0 < 128; k0 += 32) {
#pragma unroll
    for (int rds = 0; rds < 2; rds++) {
      int idx = (rds * 256 + tid) * 8;
      int m = idx >> 5, c = idx & 31;
      int gr = row0 + m;
      if (gr >= M) gr = M - 1;
      *(uint4*)(&As[m * LDT + c]) = *(const uint4*)(A + (size_t)gr * 128 + k0 + c);
      *(uint4*)(&Bs[m * LDT + c]) = *(const uint4*)(Bt + m * 128 + k0 + c);
    }
    __syncthreads();
    bf16x8 af[4], bfr[4];
#pragma unroll
    for (int im = 0; im < 4; im++)
      af[im] = *(const bf16x8*)(&As[(wm + im * 16 + l16) * LDT + quad * 8]);
#pragma unroll
    for (int in = 0; in < 4; in++)
      bfr[in] = *(const bf16x8*)(&Bs[(wn + in * 16 + l16) * LDT + quad * 8]);
#pragma unroll
    for (int im = 0; im < 4; im++)
#pragma unroll
      for (int in = 0; in < 4; in++)
        acc[im][in] = __builtin_amdgcn_mfma_f32_16x16x32_bf16(af[im], bfr[in], acc[im][in], 0, 0, 0);
    __syncthreads();
  }
#pragma unroll
  for (int im = 0; im < 4; im++)
#pragma unroll
    for (int r = 0; r < 4; r++) {
      int row = row0 + wm + im * 16 + quad * 4 + r;
      if (row < M)
#pragma unroll
        for (int in = 0; in < 4; in++)
          C[(size_t)row * 128 + wn + in * 16 + l16] = f2b(acc[im][in][r]);
    }
}

// K3: gates[f32, N x 512] = [h_t(f32) | hpb(bf16)] @ Bc^T + bgate
__global__ __launch_bounds__(256) void gemm_gate(
    const float* __restrict__ A1, const unsigned short* __restrict__ A2,
    const unsigned short* __restrict__ Bc, const float* __restrict__ bgate,
    float* __restrict__ gates, int M) {
  __shared__ unsigned short As[128 * LDT];
  __shared__ unsigned short Bs[128 * LDT];
  const int tid = threadIdx.x;
  const int lane = tid & 63, wid = tid >> 6;
  const int quad = lane >> 4, l16 = lane & 15;
  const int row0 = blockIdx.x * 128;
  const int col0 = blockIdx.y * 128;
  const int wm = (wid >> 1) * 64, wn = (wid & 1) * 64;
  f32x4 acc[4][4] = {};
  for (int k0 = 0; k0 < 256; k0 += 32) {
#pragma unroll
    for (int rds = 0; rds < 2; rds++) {
      int idx = (rds * 256 + tid) * 8;
      int m = idx >> 5, c = idx & 31;
      int gr = row0 + m;
      if (gr >= M) gr = M - 1;
      if (k0 < 128) {
        const float4 va = *(const float4*)(A1 + (size_t)gr * (TT * DIM) + k0 + c);
        const float4 vb = *(const float4*)(A1 + (size_t)gr * (TT * DIM) + k0 + c + 4);
        unsigned short* d = &As[m * LDT + c];
        d[0] = f2b(va.x); d[1] = f2b(va.y); d[2] = f2b(va.z); d[3] = f2b(va.w);
        d[4] = f2b(vb.x); d[5] = f2b(vb.y); d[6] = f2b(vb.z); d[7] = f2b(vb.w);
      } else {
        *(uint4*)(&As[m * LDT + c]) = *(const uint4*)(A2 + (size_t)gr * 128 + (k0 - 128) + c);
      }
      int n = m;
      *(uint4*)(&Bs[n * LDT + c]) = *(const uint4*)(Bc + (size_t)(col0 + n) * 256 + k0 + c);
    }
    __syncthreads();
    bf16x8 af[4], bfr[4];
#pragma unroll
    for (int im = 0; im < 4; im++)
      af[im] = *(const bf16x8*)(&As[(wm + im * 16 + l16) * LDT + quad * 8]);
#pragma unroll
    for (int in = 0; in < 4; in++)
      bfr[in] = *(const bf16x8*)(&Bs[(wn + in * 16 + l16) * LDT + quad * 8]);
#pragma unroll
    for (int im = 0; im < 4; im++)
#pragma unroll
      for (int in = 0; in < 4; in++)
        acc[im][in] = __builtin_amdgcn_mfma_f32_16x16x32_bf16(af[im], bfr[in], acc[im][in], 0, 0, 0);
    __syncthreads();
  }
#pragma unroll
  for (int im = 0; im < 4; im++)
#pragma unroll
    for (int r = 0; r < 4; r++) {
      int row = row0 + wm + im * 16 + quad * 4 + r;
      if (row < M)
#pragma unroll
        for (int in = 0; in < 4; in++) {
          int col = col0 + wn + in * 16 + l16;
          gates[(size_t)row * 512 + col] = acc[im][in][r] + bgate[col];
        }
    }
}

// ---------------- SpMM (bf16 gather) ----------------
// spmm1: y1s[d] = bf16( ns[d] * gelu( nd[d]*sum z1[s] + bg1 ) )
__global__ __launch_bounds__(256) void spmm1_kernel(
    const unsigned short* __restrict__ z, const int* __restrict__ rowp,
    const int* __restrict__ colx, const float* __restrict__ ns,
    const float* __restrict__ nd, const float* __restrict__ bg,
    unsigned short* __restrict__ y) {
  int w = (blockIdx.x * 256 + threadIdx.x) >> 6;
  int lane = threadIdx.x & 63;
  if (w >= NN) return;
  int beg = rowp[w], end = rowp[w + 1];
  float ax = 0.f, ay = 0.f;
  for (int j = beg; j < end; j++) {
    int s = colx[j];
    unsigned v = *(const unsigned*)(z + (size_t)s * 128 + lane * 2);
    ax += b2f((unsigned short)(v & 0xffff));
    ay += b2f((unsigned short)(v >> 16));
  }
  float sc = nd[w];
  float2 b = *(const float2*)(bg + lane * 2);
  float so = ns[w];
  unsigned o = (unsigned)f2b(so * geluf_(ax * sc + b.x)) |
               ((unsigned)f2b(so * geluf_(ay * sc + b.y)) << 16);
  *(unsigned*)(y + (size_t)w * 128 + lane * 2) = o;
}

// spmm2: y2b[d] = bf16( gelu( nd[d]*sum z2[s] + bg2 ) )
__global__ __launch_bounds__(256) void spmm2_kernel(
    const unsigned short* __restrict__ z, const int* __restrict__ rowp,
    const int* __restrict__ colx, const float* __restrict__ nd,
    const float* __restrict__ bg, unsigned short* __restrict__ y) {
  int w = (blockIdx.x * 256 + threadIdx.x) >> 6;
  int lane = threadIdx.x & 63;
  if (w >= NN) return;
  int beg = rowp[w], end = rowp[w + 1];
  float ax = 0.f, ay = 0.f;
  for (int j = beg; j < end; j++) {
    int s = colx[j];
    unsigned v = *(const unsigned*)(z + (size_t)s * 128 + lane * 2);
    ax += b2f((unsigned short)(v & 0xffff));
    ay += b2f((unsigned short)(v >> 16));
  }
  float sc = nd[w];
  float2 b = *(const float2*)(bg + lane * 2);
  unsigned o = (unsigned)f2b(geluf_(ax * sc + b.x)) |
               ((unsigned)f2b(geluf_(ay * sc + b.y)) << 16);
  *(unsigned*)(y + (size_t)w * 128 + lane * 2) = o;
}

// ---------------- column mean over N rows (hs output), bf16 input ----------------

__global__ void colmean_bf16(const unsigned short* __restrict__ x, float* __restrict__ out) {
  int cc = threadIdx.x & 127;
  int half = threadIdx.x >> 7;
  float s = 0.f;
  for (int r = blockIdx.x * 2 + half; r < NN; r += 512)
    s += b2f(x[(size_t)r * 128 + cc]);
  __shared__ float sm[256];
  sm[threadIdx.x] = s;
  __syncthreads();
  if (threadIdx.x < 128)
    atomicAdd(&out[cc], (sm[threadIdx.x] + sm[threadIdx.x + 128]) * (1.0f / NN));
}

// ---------------- LSTM pointwise + running time-mean ----------------

__global__ void lstm_pw(const float* __restrict__ g4, float* __restrict__ c,
                        unsigned short* __restrict__ hpb, float* __restrict__ acc, int mode) {
  int i = blockIdx.x * 256 + threadIdx.x;
  if (i >= NN * DIM) return;
  int n = i >> 7, cc = i & 127;
  const float* g = g4 + (size_t)n * 512;
  float ig = sigmoidf_(g[cc]);
  float fg = sigmoidf_(g[DIM + cc]);
  float gg = tanhf(g[2 * DIM + cc]);
  float og = sigmoidf_(g[3 * DIM + cc]);
  float cprev = (mode == 0) ? 0.f : c[i];
  float cn = fg * cprev + ig * gg;
  float ho = og * tanhf(cn);
  c[i] = cn;
  hpb[i] = f2b(ho);
  if (mode == 0) acc[i] = ho;
  else if (mode == 1) acc[i] += ho;
  else acc[i] = (acc[i] + ho) * (1.0f / TT);
}

// ---------------- host ----------------

extern "C" void kernel_launch(void* const* d_in, const int* in_sizes, int n_in,
                              void* d_out, int out_size, void* d_ws, size_t ws_size,
                              hipStream_t stream) {
  const float* h   = (const float*)d_in[0];
  const int*   src = (const int*)d_in[1];
  const int*   dst = (const int*)d_in[2];
  const float* Wg1 = (const float*)d_in[3];
  const float* bg1 = (const float*)d_in[4];
  const float* Wg2 = (const float*)d_in[5];
  const float* bg2 = (const float*)d_in[6];
  const float* wih = (const float*)d_in[7];
  const float* whh = (const float*)d_in[8];
  const float* bih = (const float*)d_in[9];
  const float* bhh = (const float*)d_in[10];

  float* out = (float*)d_out;
  float* hs_out = out;            // 12*128
  float* ht_out = out + TT * DIM; // N*128 (used directly as running accumulator)

  char* p = (char*)d_ws;
  auto alloc = [&](size_t bytes) -> void* {
    void* r = (void*)p;
    p += (bytes + 255) & ~(size_t)255;
    return r;
  };
  unsigned short* z1t  = (unsigned short*)alloc((size_t)NN * DIM * 2);
  unsigned short* y1s  = (unsigned short*)alloc((size_t)NN * DIM * 2);
  unsigned short* z2   = (unsigned short*)alloc((size_t)NN * DIM * 2);
  unsigned short* y2b  = (unsigned short*)alloc((size_t)NN * DIM * 2);
  float* gates = (float*)alloc((size_t)NN * 512 * 4);
  float* cst   = (float*)alloc((size_t)NN * DIM * 4);
  unsigned short* hpb = (unsigned short*)alloc((size_t)NN * DIM * 2);
  unsigned short* W1bt = (unsigned short*)alloc(16384 * 2);
  unsigned short* W2bt = (unsigned short*)alloc(16384 * 2);
  unsigned short* Bc   = (unsigned short*)alloc(131072 * 2);
  float* bgate = (float*)alloc(512 * 4);
  float* ns    = (float*)alloc(NN * 4);
  float* nd    = (float*)alloc(NN * 4);
  int* degs    = (int*)alloc(NN * 4);
  int* degd    = (int*)alloc(NN * 4);
  int* rowp    = (int*)alloc((NN + 1) * 4);
  int* colx    = (int*)alloc(EE * 4);

  hipMemsetAsync(degs, 0, NN * 4, stream);
  hipMemsetAsync(degd, 0, NN * 4, stream);
  hipMemsetAsync(hs_out, 0, TT * DIM * 4, stream);
  hipMemsetAsync(hpb, 0, (size_t)NN * DIM * 2, stream);

  deg_kernel<<<(EE + 255) / 256, 256, 0, stream>>>(src, dst, degs, degd);
  norm_kernel<<<(NN + 255) / 256, 256, 0, stream>>>(degs, degd, ns, nd);
  scan_kernel<<<1, 1024, 0, stream>>>(degd, rowp, NN);
  hipMemsetAsync(degs, 0, NN * 4, stream);  // reuse as fill counters
  csr_kernel<<<(EE + 255) / 256, 256, 0, stream>>>(src, dst, rowp, degs, colx);
  prep_w<<<(16384 + 131072 + 255) / 256, 256, 0, stream>>>(Wg1, Wg2, wih, whh, bih, bhh,
                                                            W1bt, W2bt, Bc, bgate);

  const int gblocks = (NN + 127) / 128;  // 391
  const int sblocks = (NN + 3) / 4;      // wave-per-row

  for (int t = 0; t < TT; t++) {
    gemm_scaleA_f32<<<gblocks, 256, 0, stream>>>(h + (size_t)t * DIM, ns, W1bt, z1t, NN);
    spmm1_kernel<<<sblocks, 256, 0, stream>>>(z1t, rowp, colx, ns, nd, bg1, y1s);
    gemm_bf16A<<<gblocks, 256, 0, stream>>>(y1s, W2bt, z2, NN);
    spmm2_kernel<<<sblocks, 256, 0, stream>>>(z2, rowp, colx, nd, bg2, y2b);
    colmean_bf16<<<256, 256, 0, stream>>>(y2b, hs_out + t * DIM);
  }

  for (int t = 0; t < TT; t++) {
    gemm_gate<<<dim3(gblocks, 4), 256, 0, stream>>>(h + (size_t)t * DIM, hpb, Bc, bgate,
                                                     gates, NN);
    int mode = (t == 0) ? 0 : (t == TT - 1 ? 2 : 1);
    lstm_pw<<<(NN * DIM + 255) / 256, 256, 0, stream>>>(gates, cst, hpb, ht_out, mode);
  }
}

// Round 3
// 2565.712 us; speedup vs baseline: 2.6068x; 1.5722x over previous
//
#include <hip/hip_runtime.h>
#include <math.h>

#define NN 50000
#define TT 12
#define EE 800000
#define DIM 128

typedef short bf16x8 __attribute__((ext_vector_type(8)));
typedef float f32x4 __attribute__((ext_vector_type(4)));

__device__ __forceinline__ float sigmoidf_(float x) { return 1.0f / (1.0f + expf(-x)); }
__device__ __forceinline__ float geluf_(float x) {
  return 0.5f * x * (1.0f + erff(x * 0.70710678118654752440f));
}
__device__ __forceinline__ unsigned short f2b(float f) {
  union { float f; unsigned u; } v;
  v.f = f;
  unsigned r = (v.u + 0x7fffu + ((v.u >> 16) & 1u)) >> 16;
  return (unsigned short)r;
}
__device__ __forceinline__ float blo(unsigned u) {
  union { unsigned x; float f; } v; v.x = u << 16; return v.f;
}
__device__ __forceinline__ float bhi(unsigned u) {
  union { unsigned x; float f; } v; v.x = u & 0xffff0000u; return v.f;
}
__device__ __forceinline__ float b2f(unsigned short b) {
  union { unsigned u; float f; } v; v.u = ((unsigned)b) << 16; return v.f;
}

// ---------------- graph preprocessing ----------------

__global__ void deg_kernel(const int* __restrict__ src, const int* __restrict__ dst,
                           int* __restrict__ ds, int* __restrict__ dd) {
  int e = blockIdx.x * 256 + threadIdx.x;
  if (e < EE) {
    atomicAdd(&ds[src[e]], 1);
    atomicAdd(&dd[dst[e]], 1);
  }
}

__global__ void norm_kernel(const int* __restrict__ ds, const int* __restrict__ dd,
                            float* __restrict__ ns, float* __restrict__ nd) {
  int i = blockIdx.x * 256 + threadIdx.x;
  if (i < NN) {
    ns[i] = rsqrtf((float)(ds[i] > 1 ? ds[i] : 1));
    nd[i] = rsqrtf((float)(dd[i] > 1 ? dd[i] : 1));
  }
}

__global__ void scan_kernel(const int* __restrict__ cnt, int* __restrict__ row_ptr, int n) {
  __shared__ int sm[1024];
  __shared__ int carry;
  int tid = threadIdx.x;
  if (tid == 0) carry = 0;
  __syncthreads();
  for (int base = 0; base < n; base += 1024) {
    int v = (base + tid < n) ? cnt[base + tid] : 0;
    sm[tid] = v;
    __syncthreads();
    for (int off = 1; off < 1024; off <<= 1) {
      int t = (tid >= off) ? sm[tid - off] : 0;
      __syncthreads();
      sm[tid] += t;
      __syncthreads();
    }
    int incl = sm[tid];
    if (base + tid < n) row_ptr[base + tid] = carry + incl - v;
    int tot = sm[1023];
    __syncthreads();
    if (tid == 0) carry += tot;
    __syncthreads();
  }
  if (tid == 0) row_ptr[n] = carry;
}

__global__ void csr_kernel(const int* __restrict__ src, const int* __restrict__ dst,
                           const int* __restrict__ row_ptr, int* __restrict__ fill,
                           int* __restrict__ col) {
  int e = blockIdx.x * 256 + threadIdx.x;
  if (e < EE) {
    int d = dst[e];
    int pos = row_ptr[d] + atomicAdd(&fill[d], 1);
    col[pos] = src[e];
  }
}

// ---------------- weight prep ----------------

__global__ void prep_w(const float* __restrict__ Wg1, const float* __restrict__ Wg2,
                       const float* __restrict__ wih, const float* __restrict__ whh,
                       const float* __restrict__ bih, const float* __restrict__ bhh,
                       unsigned short* __restrict__ W1bt, unsigned short* __restrict__ W2bt,
                       unsigned short* __restrict__ Bc, float* __restrict__ bgate) {
  int i = blockIdx.x * 256 + threadIdx.x;
  if (i < 16384) {
    int n = i >> 7, k = i & 127;
    W1bt[n * 128 + k] = f2b(Wg1[k * 128 + n]);
    W2bt[n * 128 + k] = f2b(Wg2[k * 128 + n]);
  }
  int j = i - 16384;
  if (j >= 0 && j < 131072) {
    int n = j >> 8, k = j & 255;
    Bc[j] = f2b(k < 128 ? wih[n * 128 + k] : whh[n * 128 + (k - 128)]);
  }
  if (i < 512) bgate[i] = bih[i] + bhh[i];
}

// ---------------- batched MFMA GEMMs (M = 600000, K = 128, N = 128) ----------------
#define LDT 40

// z1[(n,t)] = bf16( ns[n] * h[(n,t)] ) @ W1bt^T
__global__ __launch_bounds__(256) void gemm_scaleA_f32(
    const float* __restrict__ A, const float* __restrict__ ns,
    const unsigned short* __restrict__ Bt, unsigned short* __restrict__ C, int M) {
  __shared__ unsigned short As[128 * LDT];
  __shared__ unsigned short Bs[128 * LDT];
  const int tid = threadIdx.x;
  const int lane = tid & 63, wid = tid >> 6;
  const int quad = lane >> 4, l16 = lane & 15;
  const int row0 = blockIdx.x * 128;
  const int wm = (wid >> 1) * 64, wn = (wid & 1) * 64;
  f32x4 acc[4][4] = {};
  for (int k0 = 0; k0 < 128; k0 += 32) {
#pragma unroll
    for (int rds = 0; rds < 2; rds++) {
      int idx = (rds * 256 + tid) * 8;
      int m = idx >> 5, c = idx & 31;
      int gr = row0 + m;
      if (gr >= M) gr = M - 1;
      float s = ns[gr / TT];
      const float4 va = *(const float4*)(A + (size_t)gr * 128 + k0 + c);
      const float4 vb = *(const float4*)(A + (size_t)gr * 128 + k0 + c + 4);
      unsigned short* d = &As[m * LDT + c];
      d[0] = f2b(va.x * s); d[1] = f2b(va.y * s); d[2] = f2b(va.z * s); d[3] = f2b(va.w * s);
      d[4] = f2b(vb.x * s); d[5] = f2b(vb.y * s); d[6] = f2b(vb.z * s); d[7] = f2b(vb.w * s);
      *(uint4*)(&Bs[m * LDT + c]) = *(const uint4*)(Bt + m * 128 + k0 + c);
    }
    __syncthreads();
    bf16x8 af[4], bfr[4];
#pragma unroll
    for (int im = 0; im < 4; im++)
      af[im] = *(const bf16x8*)(&As[(wm + im * 16 + l16) * LDT + quad * 8]);
#pragma unroll
    for (int in = 0; in < 4; in++)
      bfr[in] = *(const bf16x8*)(&Bs[(wn + in * 16 + l16) * LDT + quad * 8]);
#pragma unroll
    for (int im = 0; im < 4; im++)
#pragma unroll
      for (int in = 0; in < 4; in++)
        acc[im][in] = __builtin_amdgcn_mfma_f32_16x16x32_bf16(af[im], bfr[in], acc[im][in], 0, 0, 0);
    __syncthreads();
  }
#pragma unroll
  for (int im = 0; im < 4; im++)
#pragma unroll
    for (int r = 0; r < 4; r++) {
      int row = row0 + wm + im * 16 + quad * 4 + r;
      if (row < M)
#pragma unroll
        for (int in = 0; in < 4; in++)
          C[(size_t)row * 128 + wn + in * 16 + l16] = f2b(acc[im][in][r]);
    }
}

// z2 = y1s @ W2bt^T  (bf16 A)
__global__ __launch_bounds__(256) void gemm_bf16A(
    const unsigned short* __restrict__ A, const unsigned short* __restrict__ Bt,
    unsigned short* __restrict__ C, int M) {
  __shared__ unsigned short As[128 * LDT];
  __shared__ unsigned short Bs[128 * LDT];
  const int tid = threadIdx.x;
  const int lane = tid & 63, wid = tid >> 6;
  const int quad = lane >> 4, l16 = lane & 15;
  const int row0 = blockIdx.x * 128;
  const int wm = (wid >> 1) * 64, wn = (wid & 1) * 64;
  f32x4 acc[4][4] = {};
  for (int k0 = 0; k0 < 128; k0 += 32) {
#pragma unroll
    for (int rds = 0; rds < 2; rds++) {
      int idx = (rds * 256 + tid) * 8;
      int m = idx >> 5, c = idx & 31;
      int gr = row0 + m;
      if (gr >= M) gr = M - 1;
      *(uint4*)(&As[m * LDT + c]) = *(const uint4*)(A + (size_t)gr * 128 + k0 + c);
      *(uint4*)(&Bs[m * LDT + c]) = *(const uint4*)(Bt + m * 128 + k0 + c);
    }
    __syncthreads();
    bf16x8 af[4], bfr[4];
#pragma unroll
    for (int im = 0; im < 4; im++)
      af[im] = *(const bf16x8*)(&As[(wm + im * 16 + l16) * LDT + quad * 8]);
#pragma unroll
    for (int in = 0; in < 4; in++)
      bfr[in] = *(const bf16x8*)(&Bs[(wn + in * 16 + l16) * LDT + quad * 8]);
#pragma unroll
    for (int im = 0; im < 4; im++)
#pragma unroll
      for (int in = 0; in < 4; in++)
        acc[im][in] = __builtin_amdgcn_mfma_f32_16x16x32_bf16(af[im], bfr[in], acc[im][in], 0, 0, 0);
    __syncthreads();
  }
#pragma unroll
  for (int im = 0; im < 4; im++)
#pragma unroll
    for (int r = 0; r < 4; r++) {
      int row = row0 + wm + im * 16 + quad * 4 + r;
      if (row < M)
#pragma unroll
        for (int in = 0; in < 4; in++)
          C[(size_t)row * 128 + wn + in * 16 + l16] = f2b(acc[im][in][r]);
    }
}

// ---------------- batched SpMM: per dst row gather 12x128 bf16 (3 KB) per edge ----
// y[(d,t)] = bf16( [ns[d]] * gelu( nd[d]*sum_s z[(s,t)] + bg ) )
template <bool SCALE_OUT>
__global__ __launch_bounds__(256) void spmm_b(
    const unsigned short* __restrict__ z, const int* __restrict__ rowp,
    const int* __restrict__ colx, const float* __restrict__ ns,
    const float* __restrict__ nd, const float* __restrict__ bg,
    unsigned short* __restrict__ y) {
  int d = (blockIdx.x * 256 + threadIdx.x) >> 6;
  int lane = threadIdx.x & 63;
  if (d >= NN) return;
  int beg = rowp[d], end = rowp[d + 1];
  float acc[3][8] = {};
  int j = beg;
  int s = (j < end) ? colx[j] : 0;
  while (j < end) {
    int snext = (j + 1 < end) ? colx[j + 1] : 0;
    const unsigned short* base = z + (size_t)s * 1536 + lane * 8;
#pragma unroll
    for (int r = 0; r < 3; r++) {
      uint4 v = *(const uint4*)(base + r * 512);
      acc[r][0] += blo(v.x); acc[r][1] += bhi(v.x);
      acc[r][2] += blo(v.y); acc[r][3] += bhi(v.y);
      acc[r][4] += blo(v.z); acc[r][5] += bhi(v.z);
      acc[r][6] += blo(v.w); acc[r][7] += bhi(v.w);
    }
    s = snext;
    j++;
  }
  float scn = nd[d];
  float sco = SCALE_OUT ? ns[d] : 1.0f;
  float bgv[8];
#pragma unroll
  for (int k = 0; k < 8; k++) bgv[k] = bg[(lane * 8 + k) & 127];
  unsigned short* outp = y + (size_t)d * 1536 + lane * 8;
#pragma unroll
  for (int r = 0; r < 3; r++) {
    unsigned short o[8];
#pragma unroll
    for (int k = 0; k < 8; k++)
      o[k] = f2b(sco * geluf_(acc[r][k] * scn + bgv[k]));
    *(uint4*)(outp + r * 512) = *(const uint4*)o;
  }
}

// ---------------- batched column mean: hs[t] = mean_n y2[(n,t)] ----------------

__global__ void colmean_b(const unsigned short* __restrict__ x, float* __restrict__ out) {
  int t = blockIdx.x;
  int cc = threadIdx.x & 127;
  int half = threadIdx.x >> 7;
  float s = 0.f;
  for (int n = blockIdx.y * 2 + half; n < NN; n += 64)
    s += b2f(x[((size_t)n * TT + t) * 128 + cc]);
  __shared__ float sm[256];
  sm[threadIdx.x] = s;
  __syncthreads();
  if (threadIdx.x < 128)
    atomicAdd(&out[t * 128 + cc], (sm[threadIdx.x] + sm[threadIdx.x + 128]) * (1.0f / NN));
}

// ---------------- LSTM megakernel: all 12 steps, c + ht-acc in registers -------
// block = 512 thr (8 waves), 64 rows x 512 gate-cols. Wave w covers cols
// {g*128 + w*16 + l16 : g in 0..3}. Hidden state round-trips through LDS only.
#define HPLD 132

__global__ __launch_bounds__(512, 2) void lstm_all(
    const float* __restrict__ h, const unsigned short* __restrict__ Bc,
    const float* __restrict__ bgate, float* __restrict__ ht_out, int M) {
  __shared__ unsigned short As[64 * LDT];
  __shared__ unsigned short Bs[512 * LDT];
  __shared__ unsigned short Hp[64 * HPLD];
  const int tid = threadIdx.x;
  const int lane = tid & 63, w = tid >> 6;
  const int quad = lane >> 4, l16 = lane & 15;
  const int row0 = blockIdx.x * 64;
  const int colg = w * 16 + l16;

  float cs[4][4], hacc[4][4];
#pragma unroll
  for (int im = 0; im < 4; im++)
#pragma unroll
    for (int r = 0; r < 4; r++) { cs[im][r] = 0.f; hacc[im][r] = 0.f; }

  for (int i = tid; i < 64 * HPLD / 2; i += 512) ((unsigned*)Hp)[i] = 0u;

  const float bi = bgate[colg], bff = bgate[128 + colg];
  const float bgg = bgate[256 + colg], bo = bgate[384 + colg];
  __syncthreads();

  for (int t = 0; t < TT; t++) {
    f32x4 acc[4][4] = {};  // [im][gate]
    for (int k0 = 0; k0 < 256; k0 += 32) {
      if (k0 < 128) {
        int idx = tid * 4;
        int m = idx >> 5, c = idx & 31;
        int gr = row0 + m;
        if (gr >= M) gr = M - 1;
        const float4 va = *(const float4*)(h + ((size_t)gr * TT + t) * 128 + k0 + c);
        unsigned short tmp[4] = {f2b(va.x), f2b(va.y), f2b(va.z), f2b(va.w)};
        *(uint2*)(&As[m * LDT + c]) = *(const uint2*)tmp;
      }
#pragma unroll
      for (int it = 0; it < 4; it++) {
        int jj = (it * 512 + tid) * 8;
        int n = jj >> 5, cc = jj & 31;
        *(uint4*)(&Bs[n * LDT + cc]) = *(const uint4*)(Bc + (size_t)n * 256 + k0 + cc);
      }
      __syncthreads();
      bf16x8 af[4];
      if (k0 < 128) {
#pragma unroll
        for (int im = 0; im < 4; im++)
          af[im] = *(const bf16x8*)(&As[(im * 16 + l16) * LDT + quad * 8]);
      } else {
#pragma unroll
        for (int im = 0; im < 4; im++)
          af[im] = *(const bf16x8*)(&Hp[(im * 16 + l16) * HPLD + (k0 - 128) + quad * 8]);
      }
#pragma unroll
      for (int g = 0; g < 4; g++) {
        bf16x8 bf = *(const bf16x8*)(&Bs[(g * 128 + colg) * LDT + quad * 8]);
#pragma unroll
        for (int im = 0; im < 4; im++)
          acc[im][g] = __builtin_amdgcn_mfma_f32_16x16x32_bf16(af[im], bf, acc[im][g], 0, 0, 0);
      }
      __syncthreads();
    }
    // fused pointwise; h stays in LDS, c stays in registers
#pragma unroll
    for (int im = 0; im < 4; im++)
#pragma unroll
      for (int r = 0; r < 4; r++) {
        float iv = sigmoidf_(acc[im][0][r] + bi);
        float fv = sigmoidf_(acc[im][1][r] + bff);
        float gv = tanhf(acc[im][2][r] + bgg);
        float ov = sigmoidf_(acc[im][3][r] + bo);
        float cn = fv * cs[im][r] + iv * gv;
        cs[im][r] = cn;
        float ho = ov * tanhf(cn);
        hacc[im][r] += ho;
        Hp[(im * 16 + quad * 4 + r) * HPLD + colg] = f2b(ho);
      }
    __syncthreads();
  }
#pragma unroll
  for (int im = 0; im < 4; im++)
#pragma unroll
    for (int r = 0; r < 4; r++) {
      int gr = row0 + im * 16 + quad * 4 + r;
      if (gr < M) ht_out[(size_t)gr * 128 + colg] = hacc[im][r] * (1.0f / TT);
    }
}

// ---------------- host ----------------

extern "C" void kernel_launch(void* const* d_in, const int* in_sizes, int n_in,
                              void* d_out, int out_size, void* d_ws, size_t ws_size,
                              hipStream_t stream) {
  const float* h   = (const float*)d_in[0];
  const int*   src = (const int*)d_in[1];
  const int*   dst = (const int*)d_in[2];
  const float* Wg1 = (const float*)d_in[3];
  const float* bg1 = (const float*)d_in[4];
  const float* Wg2 = (const float*)d_in[5];
  const float* bg2 = (const float*)d_in[6];
  const float* wih = (const float*)d_in[7];
  const float* whh = (const float*)d_in[8];
  const float* bih = (const float*)d_in[9];
  const float* bhh = (const float*)d_in[10];

  float* out = (float*)d_out;
  float* hs_out = out;            // 12*128
  float* ht_out = out + TT * DIM; // N*128

  char* p = (char*)d_ws;
  auto alloc = [&](size_t bytes) -> void* {
    void* r = (void*)p;
    p += (bytes + 255) & ~(size_t)255;
    return r;
  };
  const size_t MB = (size_t)NN * TT * DIM;  // 76.8M elements
  unsigned short* bufA = (unsigned short*)alloc(MB * 2);  // z1 -> z2
  unsigned short* bufB = (unsigned short*)alloc(MB * 2);  // y1s -> y2
  unsigned short* W1bt = (unsigned short*)alloc(16384 * 2);
  unsigned short* W2bt = (unsigned short*)alloc(16384 * 2);
  unsigned short* Bc   = (unsigned short*)alloc(131072 * 2);
  float* bgate = (float*)alloc(512 * 4);
  float* ns    = (float*)alloc(NN * 4);
  float* nd    = (float*)alloc(NN * 4);
  int* degs    = (int*)alloc(NN * 4);
  int* degd    = (int*)alloc(NN * 4);
  int* rowp    = (int*)alloc((NN + 1) * 4);
  int* colx    = (int*)alloc(EE * 4);

  hipMemsetAsync(degs, 0, NN * 4, stream);
  hipMemsetAsync(degd, 0, NN * 4, stream);
  hipMemsetAsync(hs_out, 0, TT * DIM * 4, stream);

  deg_kernel<<<(EE + 255) / 256, 256, 0, stream>>>(src, dst, degs, degd);
  norm_kernel<<<(NN + 255) / 256, 256, 0, stream>>>(degs, degd, ns, nd);
  scan_kernel<<<1, 1024, 0, stream>>>(degd, rowp, NN);
  hipMemsetAsync(degs, 0, NN * 4, stream);  // reuse as fill counters
  csr_kernel<<<(EE + 255) / 256, 256, 0, stream>>>(src, dst, rowp, degs, colx);
  prep_w<<<(16384 + 131072 + 255) / 256, 256, 0, stream>>>(Wg1, Wg2, wih, whh, bih, bhh,
                                                            W1bt, W2bt, Bc, bgate);

  const int M = NN * TT;                  // 600000 batched rows
  const int gblocks = (M + 127) / 128;    // 4688
  const int sblocks = (NN + 3) / 4;       // wave per dst row

  // GCN, batched over all 12 time steps
  gemm_scaleA_f32<<<gblocks, 256, 0, stream>>>(h, ns, W1bt, bufA, M);
  spmm_b<true><<<sblocks, 256, 0, stream>>>(bufA, rowp, colx, ns, nd, bg1, bufB);
  gemm_bf16A<<<gblocks, 256, 0, stream>>>(bufB, W2bt, bufA, M);
  spmm_b<false><<<sblocks, 256, 0, stream>>>(bufA, rowp, colx, ns, nd, bg2, bufB);
  colmean_b<<<dim3(TT, 32), 256, 0, stream>>>(bufB, hs_out);

  // LSTM: one kernel, all 12 steps
  lstm_all<<<(NN + 63) / 64, 512, 0, stream>>>(h, Bc, bgate, ht_out, NN);
}